// Round 2
// baseline (223.967 us; speedup 1.0000x reference)
//
#include <hip/hip_runtime.h>

#define RES   256
#define NPIX  (RES * RES)
#define NTRI  1000
#define EPSF  1e-8f
#define RECF  12   // floats per triangle record (9 coeffs, mn, inv, pad)

// ---------------------------------------------------------------------------
// Kernel A: one block per (batch, triangle). Project vertices, build edge
// coefficients, reduce min/max of score over the 256x256 pixel grid.
// Record: [a0,b0,c0, a1,b1,c1, a2,b2,c2, mn, inv_range, pad]
// ---------------------------------------------------------------------------
__global__ __launch_bounds__(256) void tri_setup_minmax(
    const float* __restrict__ meshes, const float* __restrict__ Km,
    const int* __restrict__ midx, const float* __restrict__ cams,
    float* __restrict__ rec)
{
    const int blk = blockIdx.x;
    const int b = blk / NTRI;
    const int t = blk - b * NTRI;
    const float* cam = cams + b * 12;

    // M = K @ cam  (3x4), computed redundantly by every thread (cheap)
    float M[12];
#pragma unroll
    for (int i = 0; i < 3; ++i) {
        const float k0 = Km[i * 3 + 0], k1 = Km[i * 3 + 1], k2 = Km[i * 3 + 2];
#pragma unroll
        for (int j = 0; j < 4; ++j)
            M[i * 4 + j] = k0 * cam[j] + k1 * cam[4 + j] + k2 * cam[8 + j];
    }

    const int m = midx[b];
    const float* tv = meshes + ((size_t)m * NTRI + t) * 9;
    float vx[3], vy[3];
#pragma unroll
    for (int v = 0; v < 3; ++v) {
        const float X = tv[v * 3 + 0], Y = tv[v * 3 + 1], Z = tv[v * 3 + 2];
        const float w  = M[8] * X + M[9] * Y + M[10] * Z + M[11] + EPSF;
        const float xp = M[0] * X + M[1] * Y + M[2]  * Z + M[3];
        const float yp = M[4] * X + M[5] * Y + M[6]  * Z + M[7];
        vx[v] = xp / w;
        vy[v] = yp / w;
    }

    const float e0x = vx[1] - vx[0], e0y = vy[1] - vy[0];
    const float e1x = vx[2] - vx[1], e1y = vy[2] - vy[1];
    const float e2x = vx[0] - vx[2], e2y = vy[0] - vy[2];
    const float N = e0x * e2y - e0y * e2x + EPSF;

    // edge_term = N*(e.y*px - e.x*py + (e.x*v.y - e.y*v.x)) = a*px + b*py + c
    const float a0 = N * e0y, b0 = -N * e0x, c0 = N * (e0x * vy[0] - e0y * vx[0]);
    const float a1 = N * e1y, b1 = -N * e1x, c1 = N * (e1x * vy[1] - e1y * vx[1]);
    const float a2 = N * e2y, b2 = -N * e2x, c2 = N * (e2x * vy[2] - e2y * vx[2]);

    float mn = INFINITY, mx = -INFINITY;
    for (int p = threadIdx.x; p < NPIX; p += 256) {
        const float fx = (float)(p >> 8);
        const float fy = (float)(p & (RES - 1));
        const float t1 = fmaxf(fmaf(a0, fx, fmaf(b0, fy, c0)), 0.0f);
        const float t2 = fmaxf(fmaf(a1, fx, fmaf(b1, fy, c1)), 0.0f);
        const float t3 = fmaxf(fmaf(a2, fx, fmaf(b2, fy, c2)), 0.0f);
        const float s = t1 * t2 * t3;
        mn = fminf(mn, s);
        mx = fmaxf(mx, s);
    }

    // wave64 butterfly then cross-wave LDS reduce
#pragma unroll
    for (int off = 32; off > 0; off >>= 1) {
        mn = fminf(mn, __shfl_down(mn, off, 64));
        mx = fmaxf(mx, __shfl_down(mx, off, 64));
    }
    __shared__ float smn[4], smx[4];
    const int lane = threadIdx.x & 63, wv = threadIdx.x >> 6;
    if (lane == 0) { smn[wv] = mn; smx[wv] = mx; }
    __syncthreads();
    if (threadIdx.x == 0) {
        mn = fminf(fminf(smn[0], smn[1]), fminf(smn[2], smn[3]));
        mx = fmaxf(fmaxf(smx[0], smx[1]), fmaxf(smx[2], smx[3]));
        float* r = rec + ((size_t)b * NTRI + t) * RECF;
        r[0] = a0; r[1] = b0; r[2] = c0;
        r[3] = a1; r[4] = b1; r[5] = c1;
        r[6] = a2; r[7] = b2; r[8] = c2;
        r[9] = mn; r[10] = 1.0f / (mx - mn + EPSF); r[11] = 0.0f;
    }
}

// ---------------------------------------------------------------------------
// Kernel B: 256 blocks per batch, one thread per pixel. Triangle table in LDS
// (uniform broadcast reads), accumulate tanh of normalized score.
// ---------------------------------------------------------------------------
__global__ __launch_bounds__(256) void rasterize(
    const float* __restrict__ rec, float* __restrict__ out)
{
    __shared__ float tri[NTRI * RECF];  // 48 KB
    const int b   = blockIdx.x >> 8;          // 256 pixel-blocks per batch
    const int pix = ((blockIdx.x & 255) << 8) + threadIdx.x;

    const float4* s4 = (const float4*)(rec + (size_t)b * NTRI * RECF);
    float4* d4 = (float4*)tri;
    for (int i = threadIdx.x; i < NTRI * RECF / 4; i += 256) d4[i] = s4[i];
    __syncthreads();

    const float fx = (float)(pix >> 8);
    const float fy = (float)(pix & (RES - 1));
    float acc = 0.0f;

    for (int t = 0; t < NTRI; ++t) {
        const float* r = &tri[t * RECF];
        const float t1 = fmaxf(fmaf(r[0], fx, fmaf(r[1], fy, r[2])), 0.0f);
        const float t2 = fmaxf(fmaf(r[3], fx, fmaf(r[4], fy, r[5])), 0.0f);
        const float t3 = fmaxf(fmaf(r[6], fx, fmaf(r[7], fy, r[8])), 0.0f);
        const float s = t1 * t2 * t3;
        const float x = (s - r[9]) * r[10];
        // tanh(x) for x >= 0: (1 - e^-2x) / (1 + e^-2x)
        const float e = __expf(-2.0f * x);
        acc += __fdividef(1.0f - e, 1.0f + e);
    }
    out[(size_t)b * NPIX + pix] = acc;
}

extern "C" void kernel_launch(void* const* d_in, const int* in_sizes, int n_in,
                              void* d_out, int out_size, void* d_ws, size_t ws_size,
                              hipStream_t stream)
{
    const float* meshes = (const float*)d_in[0];
    const float* Km     = (const float*)d_in[1];
    const int*   midx   = (const int*)d_in[2];
    const float* cams   = (const float*)d_in[3];
    float* out = (float*)d_out;
    float* rec = (float*)d_ws;          // batch * NTRI * RECF floats = 96 KB

    const int batch = in_sizes[3] / 12; // camera_poses is (B,3,4)

    tri_setup_minmax<<<dim3(batch * NTRI), dim3(256), 0, stream>>>(
        meshes, Km, midx, cams, rec);
    rasterize<<<dim3(batch * (NPIX / 256)), dim3(256), 0, stream>>>(rec, out);
}

// Round 5
// 132.901 us; speedup vs baseline: 1.6852x; 1.6852x over previous
//
#include <hip/hip_runtime.h>

#define RES    256
#define NPIX   (RES * RES)
#define NTRI   1000
#define EPSF   1e-8f
#define RECF   16          // dwords per triangle record
#define TC     8           // triangle chunks in rasterize
#define TPC    (NTRI / TC)
#define LOG2E2 2.8853900817779268f   // 2*log2(e)

// record layout (16 dwords):
//  [0..8]  a0,b0,c0,a1,b1,c1,a2,b2,c2   (edge_i(px,py) = a*px + b*py + c)
//  [9]     mn        [10] inv2k = 2*log2e/(mx-mn+eps)    [11] pad
//  [12..15] (int) bx0,bx1,by0,by1  conservative pixel bbox (empty => skip)

// ---------------------------------------------------------------------------
// Kernel A: one block per (batch, triangle). Project, build coefficients,
// bbox, then min/max of score over bbox pixels only (pow2-padded indexing).
// mn is forced to 0 unless the bbox covers the whole grid (outside pixels
// have s == 0 exactly in both our and the reference arithmetic).
// ---------------------------------------------------------------------------
__global__ __launch_bounds__(256) void tri_setup(
    const float* __restrict__ meshes, const float* __restrict__ Km,
    const int* __restrict__ midx, const float* __restrict__ cams,
    float* __restrict__ rec)
{
    const int blk = blockIdx.x;
    const int b = blk / NTRI;
    const int t = blk - b * NTRI;
    const float* cam = cams + b * 12;

    float M[12];
#pragma unroll
    for (int i = 0; i < 3; ++i) {
        const float k0 = Km[i*3+0], k1 = Km[i*3+1], k2 = Km[i*3+2];
#pragma unroll
        for (int j = 0; j < 4; ++j)
            M[i*4+j] = k0*cam[j] + k1*cam[4+j] + k2*cam[8+j];
    }
    const int m = midx[b];
    const float* tv = meshes + ((size_t)m * NTRI + t) * 9;
    float vx[3], vy[3];
#pragma unroll
    for (int v = 0; v < 3; ++v) {
        const float X = tv[v*3+0], Y = tv[v*3+1], Z = tv[v*3+2];
        const float w  = M[8]*X + M[9]*Y + M[10]*Z + M[11] + EPSF;
        vx[v] = (M[0]*X + M[1]*Y + M[2]*Z + M[3]) / w;
        vy[v] = (M[4]*X + M[5]*Y + M[6]*Z + M[7]) / w;
    }

    const float e0x = vx[1]-vx[0], e0y = vy[1]-vy[0];
    const float e1x = vx[2]-vx[1], e1y = vy[2]-vy[1];
    const float e2x = vx[0]-vx[2], e2y = vy[0]-vy[2];
    const float N = e0x*e2y - e0y*e2x + EPSF;

    const float a0 = N*e0y, b0 = -N*e0x, c0 = N*(e0x*vy[0] - e0y*vx[0]);
    const float a1 = N*e1y, b1 = -N*e1x, c1 = N*(e1x*vy[1] - e1y*vx[1]);
    const float a2 = N*e2y, b2 = -N*e2x, c2 = N*(e2x*vy[2] - e2y*vx[2]);

    // conservative bbox (clamped to sane float range before int cast)
    float mnx = fminf(fminf(vx[0],vx[1]),vx[2]);
    float mxx = fmaxf(fmaxf(vx[0],vx[1]),vx[2]);
    float mny = fminf(fminf(vy[0],vy[1]),vy[2]);
    float mxy = fmaxf(fmaxf(vy[0],vy[1]),vy[2]);
    mnx = fmaxf(fminf(mnx, 1e6f), -1e6f);  mxx = fmaxf(fminf(mxx, 1e6f), -1e6f);
    mny = fmaxf(fminf(mny, 1e6f), -1e6f);  mxy = fmaxf(fminf(mxy, 1e6f), -1e6f);
    const int bx0 = max(0,     (int)floorf(mnx) - 1);
    const int bx1 = min(RES-1, (int)ceilf (mxx) + 1);
    const int by0 = max(0,     (int)floorf(mny) - 1);
    const int by1 = min(RES-1, (int)ceilf (mxy) + 1);
    const bool empty = (bx0 > bx1) || (by0 > by1);

    float mn = INFINITY, mx = -INFINITY;
    if (!empty) {
        const int h = by1 - by0 + 1;
        int sh = 0;
        while ((1 << sh) < h) ++sh;            // hp = next pow2 >= h (<=256)
        const int hp = 1 << sh;
        const int area = (bx1 - bx0 + 1) << sh;
        for (int p = threadIdx.x; p < area; p += 256) {
            const int x = bx0 + (p >> sh);
            const int y = by0 + (p & (hp - 1));
            if (y <= by1) {
                const float fx = (float)x, fy = (float)y;
                const float t1 = fmaxf(fmaf(a0, fx, fmaf(b0, fy, c0)), 0.0f);
                const float t2 = fmaxf(fmaf(a1, fx, fmaf(b1, fy, c1)), 0.0f);
                const float t3 = fmaxf(fmaf(a2, fx, fmaf(b2, fy, c2)), 0.0f);
                const float s = t1 * t2 * t3;
                mn = fminf(mn, s);
                mx = fmaxf(mx, s);
            }
        }
    }
#pragma unroll
    for (int off = 32; off > 0; off >>= 1) {
        mn = fminf(mn, __shfl_down(mn, off, 64));
        mx = fmaxf(mx, __shfl_down(mx, off, 64));
    }
    __shared__ float smn[4], smx[4];
    const int lane = threadIdx.x & 63, wv = threadIdx.x >> 6;
    if (lane == 0) { smn[wv] = mn; smx[wv] = mx; }
    __syncthreads();
    if (threadIdx.x == 0) {
        mn = fminf(fminf(smn[0], smn[1]), fminf(smn[2], smn[3]));
        mx = fmaxf(fmaxf(smx[0], smx[1]), fmaxf(smx[2], smx[3]));
        if (empty) { mn = 0.0f; mx = 0.0f; }
        const bool fullgrid = (bx0 == 0 && bx1 == RES-1 && by0 == 0 && by1 == RES-1);
        if (!fullgrid) mn = 0.0f;   // some grid pixel is strictly outside => s==0 there
        float* r = rec + ((size_t)b * NTRI + t) * RECF;
        r[0]=a0; r[1]=b0; r[2]=c0; r[3]=a1; r[4]=b1; r[5]=c1;
        r[6]=a2; r[7]=b2; r[8]=c2; r[9]=mn;
        r[10] = LOG2E2 / (mx - mn + EPSF);
        r[11] = 0.0f;
        int* ri = (int*)r;
        ri[12]=bx0; ri[13]=bx1; ri[14]=by0; ri[15]=by1;
    }
}

// ---------------------------------------------------------------------------
// Kernel B: block = 256 threads = 4 columns x 256 rows of pixels (4 px/thread,
// same y, consecutive x). Grid = batch * 64 column-groups * TC tri-chunks.
// Per (wave, triangle): scalar bbox test (wave rect is 4 cols x 64 rows),
// skip if disjoint; else evaluate with the bit-identical fmaf tree as A.
// tanh(x) = 1 - 2/(1+e^{2x}); accumulate r = rcp(1+exp2(y2)) and a count.
// Output accumulated via atomicAdd into zeroed d_out.
// ---------------------------------------------------------------------------
__global__ __launch_bounds__(256) void rasterize(
    const float* __restrict__ rec, float* __restrict__ out)
{
    const int blk  = blockIdx.x;
    const int b    = blk / (64 * TC);
    const int rem  = blk - b * (64 * TC);
    const int tcid = rem >> 6;
    const int xg   = rem & 63;
    const int x0   = xg << 2;

    const float fy  = (float)threadIdx.x;          // y = threadIdx.x (0..255)
    const float fx0 = (float)x0;
    const float fx1 = fx0 + 1.0f, fx2 = fx0 + 2.0f, fx3 = fx0 + 3.0f;
    const int wy0 = __builtin_amdgcn_readfirstlane(threadIdx.x);  // wave's first y
    const int wy1 = wy0 + 63;

    float acc0 = 0.0f, acc1 = 0.0f, acc2 = 0.0f, acc3 = 0.0f, fcnt = 0.0f;
    const float* rbase = rec + ((size_t)b * NTRI + (size_t)tcid * TPC) * RECF;

    for (int i = 0; i < TPC; ++i) {
        const float* r  = rbase + i * RECF;
        const int*   ri = (const int*)r;
        const int bx0 = ri[12], bx1 = ri[13], by0 = ri[14], by1 = ri[15];
        if (bx1 < x0 || bx0 > x0 + 3 || by1 < wy0 || by0 > wy1) continue;

        const float a0 = r[0], b0 = r[1], c0 = r[2];
        const float a1 = r[3], b1 = r[4], c1 = r[5];
        const float a2 = r[6], b2 = r[7], c2 = r[8];
        const float mn = r[9], ik = r[10];
        const float B0 = fmaf(b0, fy, c0);
        const float B1 = fmaf(b1, fy, c1);
        const float B2 = fmaf(b2, fy, c2);

        {
            const float u1 = fmaxf(fmaf(a0, fx0, B0), 0.0f);
            const float u2 = fmaxf(fmaf(a1, fx0, B1), 0.0f);
            const float u3 = fmaxf(fmaf(a2, fx0, B2), 0.0f);
            const float e  = __builtin_amdgcn_exp2f((u1*u2*u3 - mn) * ik);
            acc0 += __builtin_amdgcn_rcpf(1.0f + e);
        }
        {
            const float u1 = fmaxf(fmaf(a0, fx1, B0), 0.0f);
            const float u2 = fmaxf(fmaf(a1, fx1, B1), 0.0f);
            const float u3 = fmaxf(fmaf(a2, fx1, B2), 0.0f);
            const float e  = __builtin_amdgcn_exp2f((u1*u2*u3 - mn) * ik);
            acc1 += __builtin_amdgcn_rcpf(1.0f + e);
        }
        {
            const float u1 = fmaxf(fmaf(a0, fx2, B0), 0.0f);
            const float u2 = fmaxf(fmaf(a1, fx2, B1), 0.0f);
            const float u3 = fmaxf(fmaf(a2, fx2, B2), 0.0f);
            const float e  = __builtin_amdgcn_exp2f((u1*u2*u3 - mn) * ik);
            acc2 += __builtin_amdgcn_rcpf(1.0f + e);
        }
        {
            const float u1 = fmaxf(fmaf(a0, fx3, B0), 0.0f);
            const float u2 = fmaxf(fmaf(a1, fx3, B1), 0.0f);
            const float u3 = fmaxf(fmaf(a2, fx3, B2), 0.0f);
            const float e  = __builtin_amdgcn_exp2f((u1*u2*u3 - mn) * ik);
            acc3 += __builtin_amdgcn_rcpf(1.0f + e);
        }
        fcnt += 1.0f;
    }

    float* o = out + (size_t)b * NPIX + (size_t)x0 * RES + threadIdx.x;
    atomicAdd(o,           fmaf(-2.0f, acc0, fcnt));
    atomicAdd(o + RES,     fmaf(-2.0f, acc1, fcnt));
    atomicAdd(o + 2*RES,   fmaf(-2.0f, acc2, fcnt));
    atomicAdd(o + 3*RES,   fmaf(-2.0f, acc3, fcnt));
}

extern "C" void kernel_launch(void* const* d_in, const int* in_sizes, int n_in,
                              void* d_out, int out_size, void* d_ws, size_t ws_size,
                              hipStream_t stream)
{
    const float* meshes = (const float*)d_in[0];
    const float* Km     = (const float*)d_in[1];
    const int*   midx   = (const int*)d_in[2];
    const float* cams   = (const float*)d_in[3];
    float* out = (float*)d_out;
    float* rec = (float*)d_ws;              // batch * NTRI * 16 dwords = 128 KB

    const int batch = in_sizes[3] / 12;     // camera_poses is (B,3,4)

    hipMemsetAsync(d_out, 0, (size_t)out_size * sizeof(float), stream);
    tri_setup<<<dim3(batch * NTRI), dim3(256), 0, stream>>>(
        meshes, Km, midx, cams, rec);
    rasterize<<<dim3(batch * 64 * TC), dim3(256), 0, stream>>>(rec, out);
}